// Round 1
// baseline (665.398 us; speedup 1.0000x reference)
//
#include <hip/hip_runtime.h>

#define NBINS 20
#define C 128

// ws layout: double csum[20] | unsigned cnt[20] | unsigned cor[20]  (320 B)

__global__ __launch_bounds__(256) void ece_pass1(
    const float* __restrict__ sm, const int* __restrict__ labels, int N,
    double* __restrict__ g_csum, unsigned* __restrict__ g_cnt,
    unsigned* __restrict__ g_cor) {
  __shared__ float s_csum[NBINS];
  __shared__ unsigned s_cnt[NBINS];
  __shared__ unsigned s_cor[NBINS];
  const int tid = threadIdx.x;
  if (tid < NBINS) { s_csum[tid] = 0.f; s_cnt[tid] = 0u; s_cor[tid] = 0u; }
  __syncthreads();

  const int lane = tid & 63;
  const int wave = tid >> 6;           // 0..3
  const int sub  = lane >> 5;          // half-wave: 0 or 1 (row within pair)
  const int sl   = lane & 31;          // lane within half-wave
  const long long gw    = (long long)blockIdx.x * 4 + wave;
  const long long waves = (long long)gridDim.x * 4;

  for (long long base = gw * 2; base < N; base += waves * 2) {
    const long long row = base + sub;
    float bestv = -1.f;
    int   besti = 0;
    if (row < N) {
      const float4 v = *(const float4*)(sm + row * (long long)C + sl * 4);
      bestv = v.x; besti = sl * 4;
      if (v.y > bestv) { bestv = v.y; besti = sl * 4 + 1; }
      if (v.z > bestv) { bestv = v.z; besti = sl * 4 + 2; }
      if (v.w > bestv) { bestv = v.w; besti = sl * 4 + 3; }
    }
    // max + first-index argmax across the 32-lane half-wave
    // (xor offsets <= 16 never cross the 32-lane boundary)
#pragma unroll
    for (int off = 16; off >= 1; off >>= 1) {
      const float ov = __shfl_xor(bestv, off);
      const int   oi = __shfl_xor(besti, off);
      if (ov > bestv || (ov == bestv && oi < besti)) { bestv = ov; besti = oi; }
    }
    if (sl == 0 && row < N) {
      int bin = (int)ceilf(bestv * 20.0f) - 1;   // matches jnp.ceil(conf*20)-1
      bin = min(max(bin, 0), NBINS - 1);
      const unsigned correct = (besti == labels[row]) ? 1u : 0u;
      atomicAdd(&s_csum[bin], bestv);
      atomicAdd(&s_cnt[bin], 1u);
      if (correct) atomicAdd(&s_cor[bin], 1u);
    }
  }
  __syncthreads();
  if (tid < NBINS && s_cnt[tid]) {
    atomicAdd(&g_cnt[tid], s_cnt[tid]);
    atomicAdd(&g_cor[tid], s_cor[tid]);
    atomicAdd(&g_csum[tid], (double)s_csum[tid]);
  }
}

__global__ void ece_pass2(const double* __restrict__ g_csum,
                          const unsigned* __restrict__ g_cnt,
                          const unsigned* __restrict__ g_cor,
                          float* __restrict__ out, int N) {
  const int i = threadIdx.x;
  double contrib = 0.0;
  if (i < NBINS) {
    const unsigned c = g_cnt[i];
    const double safe = c ? (double)c : 1.0;
    const double avg_conf = g_csum[i] / safe;
    const double avg_acc  = (double)g_cor[i] / safe;
    out[1 + i] = c ? (float)avg_acc : 0.f;   // ys
    if (c) contrib = fabs(avg_conf - avg_acc) * ((double)c / (double)N);
  }
#pragma unroll
  for (int off = 16; off >= 1; off >>= 1) contrib += __shfl_down(contrib, off);
  if (i == 0) out[0] = (float)contrib;       // ece
}

extern "C" void kernel_launch(void* const* d_in, const int* in_sizes, int n_in,
                              void* d_out, int out_size, void* d_ws, size_t ws_size,
                              hipStream_t stream) {
  const float* sm     = (const float*)d_in[0];
  const int*   labels = (const int*)d_in[1];
  const int N = in_sizes[1];                 // labels count = number of rows

  double*   g_csum = (double*)d_ws;
  unsigned* g_cnt  = (unsigned*)((char*)d_ws + NBINS * sizeof(double));
  unsigned* g_cor  = g_cnt + NBINS;

  // ws is re-poisoned to 0xAA before every timed launch — zero accumulators.
  hipMemsetAsync(d_ws, 0, NBINS * sizeof(double) + 2 * NBINS * sizeof(unsigned),
                 stream);

  ece_pass1<<<2048, 256, 0, stream>>>(sm, labels, N, g_csum, g_cnt, g_cor);
  ece_pass2<<<1, 64, 0, stream>>>(g_csum, g_cnt, g_cor, (float*)d_out, N);
}

// Round 2
// 655.548 us; speedup vs baseline: 1.0150x; 1.0150x over previous
//
#include <hip/hip_runtime.h>

#define NBINS 20
#define C 128

// ws layout: double csum[20] | unsigned cnt[20] | unsigned cor[20]  (320 B)

// 8 lanes per row, 4 float4 loads/lane/row-group, 2 groups (16 rows) per wave
// per iteration -> 8 independent 16B loads in flight per thread.
__global__ __launch_bounds__(256) void ece_pass1(
    const float* __restrict__ sm, const int* __restrict__ labels, int N,
    double* __restrict__ g_csum, unsigned* __restrict__ g_cnt,
    unsigned* __restrict__ g_cor) {
  __shared__ float s_csum[NBINS];
  __shared__ unsigned s_cnt[NBINS];
  __shared__ unsigned s_cor[NBINS];
  const int tid = threadIdx.x;
  if (tid < NBINS) { s_csum[tid] = 0.f; s_cnt[tid] = 0u; s_cor[tid] = 0u; }
  __syncthreads();

  const int lane = tid & 63;
  const int p = lane & 7;              // position within row (8 lanes/row)
  const int r = lane >> 3;             // row within 8-row group
  const long long gw     = (long long)blockIdx.x * 4 + (tid >> 6);
  const long long stride = (long long)gridDim.x * 4 * 16;   // rows per sweep

  for (long long base = gw * 16; base < N; base += stride) {
    float4 v[2][4];
    // Issue all 8 loads up front (independent -> 8 outstanding vmem ops).
#pragma unroll
    for (int g = 0; g < 2; ++g) {
      const long long row = base + g * 8 + r;
      if (row < N) {
        // chunk k covers float indices [k*32 + p*4, +4): byte addr row*512 + k*128 + p*16
        const float4* rp = (const float4*)(sm + row * (long long)C);
#pragma unroll
        for (int k = 0; k < 4; ++k) v[g][k] = rp[p + k * 8];
      } else {
#pragma unroll
        for (int k = 0; k < 4; ++k) v[g][k] = make_float4(-2.f, -2.f, -2.f, -2.f);
      }
    }

#pragma unroll
    for (int g = 0; g < 2; ++g) {
      // In-lane argmax over 16 values, ascending flat index -> strict '>' keeps
      // the first occurrence (matches jnp.argmax tie-break).
      float bv = -3.f;
      int bi = 0;
#pragma unroll
      for (int k = 0; k < 4; ++k) {
        const float4 q = v[g][k];
        const int b0 = k * 32 + p * 4;
        if (q.x > bv) { bv = q.x; bi = b0; }
        if (q.y > bv) { bv = q.y; bi = b0 + 1; }
        if (q.z > bv) { bv = q.z; bi = b0 + 2; }
        if (q.w > bv) { bv = q.w; bi = b0 + 3; }
      }
      // Cross-lane reduce over the 8 lanes of this row (xor 1,2,4 stay in-group).
#pragma unroll
      for (int off = 1; off <= 4; off <<= 1) {
        const float ov = __shfl_xor(bv, off);
        const int   oi = __shfl_xor(bi, off);
        if (ov > bv || (ov == bv && oi < bi)) { bv = ov; bi = oi; }
      }
      const long long row = base + g * 8 + r;
      if (p == 0 && row < N) {
        int bin = (int)ceilf(bv * 20.0f) - 1;   // matches jnp.ceil(conf*20)-1
        bin = min(max(bin, 0), NBINS - 1);
        atomicAdd(&s_csum[bin], bv);
        atomicAdd(&s_cnt[bin], 1u);
        if (bi == labels[row]) atomicAdd(&s_cor[bin], 1u);
      }
    }
  }
  __syncthreads();
  if (tid < NBINS && s_cnt[tid]) {
    atomicAdd(&g_cnt[tid], s_cnt[tid]);
    atomicAdd(&g_cor[tid], s_cor[tid]);
    atomicAdd(&g_csum[tid], (double)s_csum[tid]);
  }
}

__global__ void ece_pass2(const double* __restrict__ g_csum,
                          const unsigned* __restrict__ g_cnt,
                          const unsigned* __restrict__ g_cor,
                          float* __restrict__ out, int N) {
  const int i = threadIdx.x;
  double contrib = 0.0;
  if (i < NBINS) {
    const unsigned c = g_cnt[i];
    const double safe = c ? (double)c : 1.0;
    const double avg_conf = g_csum[i] / safe;
    const double avg_acc  = (double)g_cor[i] / safe;
    out[1 + i] = c ? (float)avg_acc : 0.f;   // ys
    if (c) contrib = fabs(avg_conf - avg_acc) * ((double)c / (double)N);
  }
#pragma unroll
  for (int off = 16; off >= 1; off >>= 1) contrib += __shfl_down(contrib, off);
  if (i == 0) out[0] = (float)contrib;       // ece
}

extern "C" void kernel_launch(void* const* d_in, const int* in_sizes, int n_in,
                              void* d_out, int out_size, void* d_ws, size_t ws_size,
                              hipStream_t stream) {
  const float* sm     = (const float*)d_in[0];
  const int*   labels = (const int*)d_in[1];
  const int N = in_sizes[1];                 // labels count = number of rows

  double*   g_csum = (double*)d_ws;
  unsigned* g_cnt  = (unsigned*)((char*)d_ws + NBINS * sizeof(double));
  unsigned* g_cor  = g_cnt + NBINS;

  // ws is re-poisoned to 0xAA before every timed launch — zero accumulators.
  hipMemsetAsync(d_ws, 0, NBINS * sizeof(double) + 2 * NBINS * sizeof(unsigned),
                 stream);

  ece_pass1<<<2048, 256, 0, stream>>>(sm, labels, N, g_csum, g_cnt, g_cor);
  ece_pass2<<<1, 64, 0, stream>>>(g_csum, g_cnt, g_cor, (float*)d_out, N);
}